// Round 4
// baseline (1803.512 us; speedup 1.0000x reference)
//
#include <hip/hip_runtime.h>
#include <cstdint>
#include <cstddef>

#define B_ROWS 16384
#define NEXP 16
#define HID 512
#define KTOT 4112   // 8*512 + 16
#define KPAD 4224   // multiple of 128 (2 K-tiles of 64 per iter)
#define EG 4        // experts per group
#define NGRP 4

typedef __attribute__((ext_vector_type(8))) short short8v;
typedef __attribute__((ext_vector_type(4))) float f32x4;

__device__ __forceinline__ float b2f(unsigned short s) {
  return __builtin_bit_cast(float, (unsigned)s << 16);
}
__device__ __forceinline__ unsigned short f2bf(float f) {
  unsigned u = __builtin_bit_cast(unsigned, f);
  return (unsigned short)((u + 0x7FFF + ((u >> 16) & 1)) >> 16);  // RNE
}

__device__ __forceinline__ void async16(void* lds, const void* g) {
  __builtin_amdgcn_global_load_lds((const __attribute__((address_space(1))) void*)g,
                                   (__attribute__((address_space(3))) void*)lds, 16, 0, 0);
}

// ---------------- pack combined -> bf16 [B][KPAD] ----------------
__global__ __launch_bounds__(256) void pack_kernel(
    const float* __restrict__ i0, const float* __restrict__ i1,
    const float* __restrict__ i2, const float* __restrict__ i3,
    const float* __restrict__ i4, const float* __restrict__ i5,
    const float* __restrict__ i6, const float* __restrict__ i7,
    const float* __restrict__ cate, unsigned short* __restrict__ comb)
{
  const long long idx = (long long)blockIdx.x * 256 + threadIdx.x;
  if (idx >= (long long)B_ROWS * (KPAD / 8)) return;
  const int b  = (int)(idx / (KPAD / 8));
  const int k8 = (int)(idx % (KPAD / 8));
  const int k  = k8 * 8;
  short8v v;
  if (k < 4096) {
    const int sel = k >> 9;
    const float* src = sel == 0 ? i0 : sel == 1 ? i1 : sel == 2 ? i2 : sel == 3 ? i3
                     : sel == 4 ? i4 : sel == 5 ? i5 : sel == 6 ? i6 : i7;
    src += (size_t)b * 512 + (k & 511);
    const float4 a = *(const float4*)(src);
    const float4 c = *(const float4*)(src + 4);
    v[0] = (short)f2bf(a.x); v[1] = (short)f2bf(a.y);
    v[2] = (short)f2bf(a.z); v[3] = (short)f2bf(a.w);
    v[4] = (short)f2bf(c.x); v[5] = (short)f2bf(c.y);
    v[6] = (short)f2bf(c.z); v[7] = (short)f2bf(c.w);
  } else if (k < KTOT) {
    const float* src = cate + (size_t)b * 16 + (k - 4096);
    const float4 a = *(const float4*)(src);
    const float4 c = *(const float4*)(src + 4);
    v[0] = (short)f2bf(a.x); v[1] = (short)f2bf(a.y);
    v[2] = (short)f2bf(a.z); v[3] = (short)f2bf(a.w);
    v[4] = (short)f2bf(c.x); v[5] = (short)f2bf(c.y);
    v[6] = (short)f2bf(c.z); v[7] = (short)f2bf(c.w);
  } else {
#pragma unroll
    for (int j = 0; j < 8; ++j) v[j] = 0;
  }
  *(short8v*)(comb + (size_t)b * KPAD + k) = v;
}

// ---------------- transpose f32 [E][Kin][N] -> bf16 [E][N][Kout] (zero-pad K) ----------------
__global__ __launch_bounds__(256) void transpose_kernel(
    const float* __restrict__ src, unsigned short* __restrict__ dst,
    int Kin, int N, int Kout)
{
  __shared__ unsigned short tile[64][68];
  const int e  = blockIdx.z;
  const int kt = blockIdx.x * 64;
  const int nt = blockIdx.y * 64;
  const int tx = threadIdx.x & 63, ty = threadIdx.x >> 6;
#pragma unroll
  for (int i = 0; i < 16; ++i) {
    const int kl = i * 4 + ty;
    const int kg = kt + kl;
    float v = (kg < Kin) ? src[((size_t)e * Kin + kg) * N + nt + tx] : 0.f;
    tile[kl][tx] = f2bf(v);
  }
  __syncthreads();
#pragma unroll
  for (int i = 0; i < 16; ++i) {
    const int nl = i * 4 + ty;
    const int kg = kt + tx;
    if (kg < Kout)
      dst[((size_t)e * N + nt + nl) * Kout + kg] = tile[tx][nl];
  }
}

// ---------------- gate ----------------
__global__ __launch_bounds__(256) void gate_kernel(
    const float* __restrict__ cate,
    const float* __restrict__ w1, const float* __restrict__ b1,
    const float* __restrict__ w2, const float* __restrict__ b2,
    float* __restrict__ gates)
{
  const int b = blockIdx.x * blockDim.x + threadIdx.x;
  if (b >= B_ROWS) return;
  float c[16];
  const float4* cp = (const float4*)(cate + (size_t)b * 16);
#pragma unroll
  for (int i = 0; i < 4; ++i) {
    float4 t = cp[i];
    c[i*4+0] = t.x; c[i*4+1] = t.y; c[i*4+2] = t.z; c[i*4+3] = t.w;
  }
  float h[8];
#pragma unroll
  for (int j = 0; j < 8; ++j) h[j] = b1[j];
#pragma unroll
  for (int i = 0; i < 16; ++i)
#pragma unroll
    for (int j = 0; j < 8; ++j) h[j] += c[i] * w1[i * 8 + j];
#pragma unroll
  for (int j = 0; j < 8; ++j) h[j] = h[j] > 0.f ? h[j] : 0.f;
  float lg[16];
#pragma unroll
  for (int k = 0; k < 16; ++k) lg[k] = b2[k];
#pragma unroll
  for (int j = 0; j < 8; ++j)
#pragma unroll
    for (int k = 0; k < 16; ++k) lg[k] += h[j] * w2[j * 16 + k];
  float mx = lg[0];
#pragma unroll
  for (int k = 1; k < 16; ++k) mx = fmaxf(mx, lg[k]);
  float s = 0.f;
#pragma unroll
  for (int k = 0; k < 16; ++k) { lg[k] = __expf(lg[k] - mx); s += lg[k]; }
  const float inv = 1.f / s;
  float4* gp = (float4*)(gates + (size_t)b * 16);
#pragma unroll
  for (int i = 0; i < 4; ++i)
    gp[i] = make_float4(lg[i*4]*inv, lg[i*4+1]*inv, lg[i*4+2]*inv, lg[i*4+3]*inv);
}

// ---------------- 256x256 8-phase bf16 GEMM (T2+T3+T4+T5) ----------------
// Out[e][M][N] = relu(A[e][M][K] * Wt[e][N][K]^T + bias[e][N]), K % 128 == 0.
// 8 waves (2M x 4N), per-wave 128x64 out = 8x4 frags of 16x16x32 MFMA.
// LDS: 2-deep double buffer, 32KB A-tile + 32KB B-tile each = 128KB.
// Round-4 change vs round-3: removed the blanket sched_barrier(0) walls
// (m141: order-pinning costs ~40%); the ONLY scheduling fence left is the
// rule-#18-required one immediately after the inline-asm lgkmcnt(0). kk is
// outermost in QUAD (16 independent MFMAs instead of 8 chains of 2), and the
// last iteration is peeled so the hot loop has no per-phase branches.
#define BAR __builtin_amdgcn_s_barrier()
#define LGKM0 do { asm volatile("s_waitcnt lgkmcnt(0)" ::: "memory"); \
                   __builtin_amdgcn_sched_barrier(0); } while(0)
#define WAITVM(n) asm volatile("s_waitcnt vmcnt(" #n ")" ::: "memory")

#define STAGE_A(buf, h, kt) do { \
  _Pragma("unroll") for (int r_ = 0; r_ < 2; ++r_) { \
    const int rl_ = (h)*128 + r_*64 + wave*8; \
    async16(&As[(buf)*16384 + rl_*64], Ae + (size_t)(rl_ + rsub)*K + (kt) + ssw); \
  } } while(0)

#define STAGE_B(buf, h, kt) do { \
  _Pragma("unroll") for (int r_ = 0; r_ < 2; ++r_) { \
    const int rl_ = (h)*128 + r_*64 + wave*8; \
    async16(&Bs[(buf)*16384 + rl_*64], We + (size_t)(rl_ + rsub)*K + (kt) + ssw); \
  } } while(0)

#define LOAD_A(buf, MH) do { \
  _Pragma("unroll") for (int mi_ = 0; mi_ < 4; ++mi_) { \
    const int R_ = wr*128 + ((MH)*4 + mi_)*16 + fr; \
    _Pragma("unroll") for (int kk_ = 0; kk_ < 2; ++kk_) \
      af[mi_][kk_] = *(const short8v*)&As[(buf)*16384 + R_*64 + (((kk_*4 + kq) ^ fr7) * 8)]; \
  } } while(0)

#define LOAD_B(buf, NH) do { \
  _Pragma("unroll") for (int ni_ = 0; ni_ < 2; ++ni_) { \
    const int R_ = wc*64 + ((NH)*2 + ni_)*16 + fr; \
    _Pragma("unroll") for (int kk_ = 0; kk_ < 2; ++kk_) \
      bf[NH][ni_][kk_] = *(const short8v*)&Bs[(buf)*16384 + R_*64 + (((kk_*4 + kq) ^ fr7) * 8)]; \
  } } while(0)

#define QUAD(MH, NH) do { \
  __builtin_amdgcn_s_setprio(1); \
  _Pragma("unroll") for (int kk_ = 0; kk_ < 2; ++kk_) \
  _Pragma("unroll") for (int mi_ = 0; mi_ < 4; ++mi_) \
  _Pragma("unroll") for (int ni_ = 0; ni_ < 2; ++ni_) \
    acc[(MH)*4 + mi_][(NH)*2 + ni_] = __builtin_amdgcn_mfma_f32_16x16x32_bf16( \
        af[mi_][kk_], bf[NH][ni_][kk_], acc[(MH)*4 + mi_][(NH)*2 + ni_], 0, 0, 0); \
  __builtin_amdgcn_s_setprio(0); \
  } while(0)

// ST is a compile-time literal (true in the hot loop, false for the peeled
// final iteration) so no per-phase branches are emitted.
#define ITER_BODY(ST) do { \
    /* P1: compute u quad(0,0); stage v.A half0 -> buf1 */ \
    LOAD_A(0, 0); LOAD_B(0, 0); \
    STAGE_A(1, 0, kt_v); \
    BAR; LGKM0; QUAD(0, 0); BAR; \
    /* P2: quad(0,1); stage v.A half1 */ \
    LOAD_B(0, 1); \
    STAGE_A(1, 1, kt_v); \
    BAR; LGKM0; QUAD(0, 1); BAR; \
    /* P3: quad(1,0); stage u2.B half0 -> buf0 */ \
    LOAD_A(0, 1); \
    if (ST) STAGE_B(0, 0, kt_u2); \
    BAR; LGKM0; QUAD(1, 0); BAR; \
    /* P4: quad(1,1); stage u2.B half1; counted vmcnt */ \
    if (ST) STAGE_B(0, 1, kt_u2); \
    BAR; QUAD(1, 1); \
    if (ST) { WAITVM(4); } else { WAITVM(0); } \
    BAR; \
    /* P5: compute v quad(0,0); stage u2.A half0 */ \
    LOAD_A(1, 0); LOAD_B(1, 0); \
    if (ST) STAGE_A(0, 0, kt_u2); \
    BAR; LGKM0; QUAD(0, 0); BAR; \
    /* P6: quad(0,1); stage u2.A half1 */ \
    LOAD_B(1, 1); \
    if (ST) STAGE_A(0, 1, kt_u2); \
    BAR; LGKM0; QUAD(0, 1); BAR; \
    /* P7: quad(1,0); stage v2.B half0 -> buf1 */ \
    LOAD_A(1, 1); \
    if (ST) STAGE_B(1, 0, kt_v2); \
    BAR; LGKM0; QUAD(1, 0); BAR; \
    /* P8: quad(1,1); stage v2.B half1; counted vmcnt */ \
    if (ST) STAGE_B(1, 1, kt_v2); \
    BAR; QUAD(1, 1); \
    if (ST) { WAITVM(4); } \
    BAR; \
  } while(0)

__global__ __launch_bounds__(512, 2) void gemm8_kernel(
    const unsigned short* __restrict__ A, const unsigned short* __restrict__ Wt,
    const float* __restrict__ bias, unsigned short* __restrict__ Out,
    int K,
    long long strideA, long long strideW, long long strideB, long long strideO)
{
  __shared__ unsigned short As[2 * 256 * 64];
  __shared__ unsigned short Bs[2 * 256 * 64];
  const int tid  = threadIdx.x;
  const int wave = tid >> 6, lane = tid & 63;
  const int wr = wave >> 2, wc = wave & 3;
  const int m0 = blockIdx.x * 256, n0 = blockIdx.y * 256;
  const int e  = blockIdx.z;
  const unsigned short* Ae = A + (size_t)e * strideA + (size_t)m0 * K;
  const unsigned short* We = Wt + (size_t)e * strideW + (size_t)n0 * K;
  const float* be = bias + (size_t)e * strideB;
  unsigned short* Oe = Out + (size_t)e * strideO;

  // staging lane geometry
  const int rsub = lane >> 3;                 // 0..7 row within 8-row block
  const int ssw  = ((lane & 7) ^ rsub) * 8;   // pre-swizzled global k-slot
  // fragment lane geometry
  const int fr  = lane & 15;
  const int kq  = lane >> 4;                  // 0..3
  const int fr7 = fr & 7;

  f32x4 acc[8][4] = {};
  short8v af[4][2];
  short8v bf[2][2][2];

  // ---- prologue: tile0 -> buf0 (B,A), tile1.B -> buf1 ----
  STAGE_B(0, 0, 0); STAGE_B(0, 1, 0);
  STAGE_A(0, 0, 0); STAGE_A(0, 1, 0);
  STAGE_B(1, 0, 64); STAGE_B(1, 1, 64);
  WAITVM(4);
  BAR;

  const int NITER = K / 128;
  int j = 0;
  for (; j < NITER - 1; ++j) {
    const int kt_v  = j * 128 + 64;
    const int kt_u2 = j * 128 + 128;
    const int kt_v2 = j * 128 + 192;
    ITER_BODY(true);
  }
  {
    const int kt_v  = j * 128 + 64;
    const int kt_u2 = 0, kt_v2 = 0;  // unused when ST=false
    (void)kt_u2; (void)kt_v2;
    ITER_BODY(false);
  }

  // ---- epilogue: bias + relu + bf16 store ----
#pragma unroll
  for (int ni = 0; ni < 4; ++ni) {
    const int n = n0 + wc * 64 + ni * 16 + fr;
    const float bv = be[n];
#pragma unroll
    for (int mi = 0; mi < 8; ++mi) {
#pragma unroll
      for (int r = 0; r < 4; ++r) {
        const int m = m0 + wr * 128 + mi * 16 + kq * 4 + r;
        float v = acc[mi][ni][r] + bv;
        v = v > 0.f ? v : 0.f;
        Oe[(size_t)m * HID + n] = f2bf(v);
      }
    }
  }
}

// ---------------- eo[e][b] = dot(h2[e_local][b][:], ew3[e][:]) + eb3[e] ----------------
__global__ __launch_bounds__(256) void eo_kernel(
    const unsigned short* __restrict__ h2, const float* __restrict__ ew3,
    const float* __restrict__ eb3, float* __restrict__ eo, int g)
{
  const int b = blockIdx.x;
  const int wave = threadIdx.x >> 6, lane = threadIdx.x & 63;
  const int e = g * EG + wave;
  const unsigned short* hp = h2 + ((size_t)wave * B_ROWS + b) * HID + lane * 8;
  const float* wp = ew3 + (size_t)e * HID + lane * 8;
  short8v hv = *(const short8v*)hp;
  float s = 0.f;
#pragma unroll
  for (int j = 0; j < 8; ++j) s += b2f((unsigned short)hv[j]) * wp[j];
#pragma unroll
  for (int off = 32; off > 0; off >>= 1) s += __shfl_xor(s, off, 64);
  if (lane == 0) eo[(size_t)e * B_ROWS + b] = s + eb3[e];
}

// ---------------- out[b] = sum_e gates[b][e] * eo[e][b] ----------------
__global__ __launch_bounds__(256) void final_kernel(
    const float* __restrict__ gates, const float* __restrict__ eo,
    float* __restrict__ out)
{
  const int b = blockIdx.x * blockDim.x + threadIdx.x;
  if (b >= B_ROWS) return;
  float s = 0.f;
#pragma unroll
  for (int e = 0; e < NEXP; ++e) s += gates[(size_t)b * 16 + e] * eo[(size_t)e * B_ROWS + b];
  out[b] = s;
}

extern "C" void kernel_launch(void* const* d_in, const int* in_sizes, int n_in,
                              void* d_out, int out_size, void* d_ws, size_t ws_size,
                              hipStream_t stream)
{
  const float* user_emb = (const float*)d_in[0];
  const float* item_emb = (const float*)d_in[1];
  const float* f_i_1    = (const float*)d_in[2];
  const float* g_i_1    = (const float*)d_in[3];
  const float* f_i_2    = (const float*)d_in[4];
  const float* g_i_2    = (const float*)d_in[5];
  const float* f_i_3    = (const float*)d_in[6];
  const float* g_i_3    = (const float*)d_in[7];
  const float* cate     = (const float*)d_in[8];
  const float* gate_w1  = (const float*)d_in[9];
  const float* gate_b1  = (const float*)d_in[10];
  const float* gate_w2  = (const float*)d_in[11];
  const float* gate_b2  = (const float*)d_in[12];
  const float* ew1      = (const float*)d_in[13];
  const float* eb1      = (const float*)d_in[14];
  const float* ew2      = (const float*)d_in[15];
  const float* eb2      = (const float*)d_in[16];
  const float* ew3      = (const float*)d_in[17];
  const float* eb3      = (const float*)d_in[18];
  float* out = (float*)d_out;

  char* ws = (char*)d_ws;
  size_t off = 0;
  unsigned short* comb = (unsigned short*)(ws + off); off += (size_t)B_ROWS * KPAD * 2;
  unsigned short* w1t  = (unsigned short*)(ws + off); off += (size_t)NEXP * HID * KPAD * 2;
  unsigned short* w2t  = (unsigned short*)(ws + off); off += (size_t)NEXP * HID * HID * 2;
  unsigned short* h1   = (unsigned short*)(ws + off); off += (size_t)EG * B_ROWS * HID * 2;
  unsigned short* h2   = (unsigned short*)(ws + off); off += (size_t)EG * B_ROWS * HID * 2;
  float* gates = (float*)(ws + off); off += (size_t)B_ROWS * NEXP * 4;
  float* eo    = (float*)(ws + off); off += (size_t)NEXP * B_ROWS * 4;

  // 1. pack combined input (bf16, K zero-padded to 4224)
  {
    const long long total = (long long)B_ROWS * (KPAD / 8);
    const int blocks = (int)((total + 255) / 256);
    pack_kernel<<<blocks, 256, 0, stream>>>(user_emb, item_emb, f_i_1, g_i_1,
                                            f_i_2, g_i_2, f_i_3, g_i_3, cate, comb);
  }
  // 2. weight transposes to [E][N][K] bf16
  transpose_kernel<<<dim3(KPAD / 64, HID / 64, NEXP), 256, 0, stream>>>(ew1, w1t, KTOT, HID, KPAD);
  transpose_kernel<<<dim3(HID / 64, HID / 64, NEXP), 256, 0, stream>>>(ew2, w2t, HID, HID, HID);
  // 3. gates
  gate_kernel<<<B_ROWS / 256, 256, 0, stream>>>(cate, gate_w1, gate_b1, gate_w2, gate_b2, gates);

  // 4. expert groups: layer1 (K=4224), layer2 (K=512), layer3 dot
  for (int g = 0; g < NGRP; ++g) {
    gemm8_kernel<<<dim3(B_ROWS / 256, HID / 256, EG), 512, 0, stream>>>(
        comb, w1t + (size_t)g * EG * HID * KPAD, eb1 + (size_t)g * EG * HID, h1,
        KPAD, 0LL, (long long)HID * KPAD, (long long)HID, (long long)B_ROWS * HID);
    gemm8_kernel<<<dim3(B_ROWS / 256, HID / 256, EG), 512, 0, stream>>>(
        h1, w2t + (size_t)g * EG * HID * HID, eb2 + (size_t)g * EG * HID, h2,
        HID, (long long)B_ROWS * HID, (long long)HID * HID, (long long)HID, (long long)B_ROWS * HID);
    eo_kernel<<<B_ROWS, 256, 0, stream>>>(h2, ew3, eb3, eo, g);
  }
  // 5. combine
  final_kernel<<<B_ROWS / 256, 256, 0, stream>>>(gates, eo, out);
}

// Round 5
// 1383.621 us; speedup vs baseline: 1.3035x; 1.3035x over previous
//
#include <hip/hip_runtime.h>
#include <cstdint>
#include <cstddef>

#define B_ROWS 16384
#define NEXP 16
#define HID 512
#define KTOT 4112   // 8*512 + 16
#define KPAD 4224   // multiple of 128 (2 K-tiles of 64 per iter)
#define EG 4        // experts per group
#define NGRP 4

typedef __attribute__((ext_vector_type(8))) short short8v;
typedef __attribute__((ext_vector_type(4))) float f32x4;

__device__ __forceinline__ float b2f(unsigned short s) {
  return __builtin_bit_cast(float, (unsigned)s << 16);
}
__device__ __forceinline__ unsigned short f2bf(float f) {
  unsigned u = __builtin_bit_cast(unsigned, f);
  return (unsigned short)((u + 0x7FFF + ((u >> 16) & 1)) >> 16);  // RNE
}

__device__ __forceinline__ void async16(void* lds, const void* g) {
  __builtin_amdgcn_global_load_lds((const __attribute__((address_space(1))) void*)g,
                                   (__attribute__((address_space(3))) void*)lds, 16, 0, 0);
}

// ---------------- pack combined -> bf16 [B][KPAD] ----------------
__global__ __launch_bounds__(256) void pack_kernel(
    const float* __restrict__ i0, const float* __restrict__ i1,
    const float* __restrict__ i2, const float* __restrict__ i3,
    const float* __restrict__ i4, const float* __restrict__ i5,
    const float* __restrict__ i6, const float* __restrict__ i7,
    const float* __restrict__ cate, unsigned short* __restrict__ comb)
{
  const long long idx = (long long)blockIdx.x * 256 + threadIdx.x;
  if (idx >= (long long)B_ROWS * (KPAD / 8)) return;
  const int b  = (int)(idx / (KPAD / 8));
  const int k8 = (int)(idx % (KPAD / 8));
  const int k  = k8 * 8;
  short8v v;
  if (k < 4096) {
    const int sel = k >> 9;
    const float* src = sel == 0 ? i0 : sel == 1 ? i1 : sel == 2 ? i2 : sel == 3 ? i3
                     : sel == 4 ? i4 : sel == 5 ? i5 : sel == 6 ? i6 : i7;
    src += (size_t)b * 512 + (k & 511);
    const float4 a = *(const float4*)(src);
    const float4 c = *(const float4*)(src + 4);
    v[0] = (short)f2bf(a.x); v[1] = (short)f2bf(a.y);
    v[2] = (short)f2bf(a.z); v[3] = (short)f2bf(a.w);
    v[4] = (short)f2bf(c.x); v[5] = (short)f2bf(c.y);
    v[6] = (short)f2bf(c.z); v[7] = (short)f2bf(c.w);
  } else if (k < KTOT) {
    const float* src = cate + (size_t)b * 16 + (k - 4096);
    const float4 a = *(const float4*)(src);
    const float4 c = *(const float4*)(src + 4);
    v[0] = (short)f2bf(a.x); v[1] = (short)f2bf(a.y);
    v[2] = (short)f2bf(a.z); v[3] = (short)f2bf(a.w);
    v[4] = (short)f2bf(c.x); v[5] = (short)f2bf(c.y);
    v[6] = (short)f2bf(c.z); v[7] = (short)f2bf(c.w);
  } else {
#pragma unroll
    for (int j = 0; j < 8; ++j) v[j] = 0;
  }
  *(short8v*)(comb + (size_t)b * KPAD + k) = v;
}

// ---------------- transpose f32 [E][Kin][N] -> bf16 [E][N][Kout] (zero-pad K) ----------------
__global__ __launch_bounds__(256) void transpose_kernel(
    const float* __restrict__ src, unsigned short* __restrict__ dst,
    int Kin, int N, int Kout)
{
  __shared__ unsigned short tile[64][68];
  const int e  = blockIdx.z;
  const int kt = blockIdx.x * 64;
  const int nt = blockIdx.y * 64;
  const int tx = threadIdx.x & 63, ty = threadIdx.x >> 6;
#pragma unroll
  for (int i = 0; i < 16; ++i) {
    const int kl = i * 4 + ty;
    const int kg = kt + kl;
    float v = (kg < Kin) ? src[((size_t)e * Kin + kg) * N + nt + tx] : 0.f;
    tile[kl][tx] = f2bf(v);
  }
  __syncthreads();
#pragma unroll
  for (int i = 0; i < 16; ++i) {
    const int nl = i * 4 + ty;
    const int kg = kt + tx;
    if (kg < Kout)
      dst[((size_t)e * N + nt + nl) * Kout + kg] = tile[tx][nl];
  }
}

// ---------------- gate ----------------
__global__ __launch_bounds__(256) void gate_kernel(
    const float* __restrict__ cate,
    const float* __restrict__ w1, const float* __restrict__ b1,
    const float* __restrict__ w2, const float* __restrict__ b2,
    float* __restrict__ gates)
{
  const int b = blockIdx.x * blockDim.x + threadIdx.x;
  if (b >= B_ROWS) return;
  float c[16];
  const float4* cp = (const float4*)(cate + (size_t)b * 16);
#pragma unroll
  for (int i = 0; i < 4; ++i) {
    float4 t = cp[i];
    c[i*4+0] = t.x; c[i*4+1] = t.y; c[i*4+2] = t.z; c[i*4+3] = t.w;
  }
  float h[8];
#pragma unroll
  for (int j = 0; j < 8; ++j) h[j] = b1[j];
#pragma unroll
  for (int i = 0; i < 16; ++i)
#pragma unroll
    for (int j = 0; j < 8; ++j) h[j] += c[i] * w1[i * 8 + j];
#pragma unroll
  for (int j = 0; j < 8; ++j) h[j] = h[j] > 0.f ? h[j] : 0.f;
  float lg[16];
#pragma unroll
  for (int k = 0; k < 16; ++k) lg[k] = b2[k];
#pragma unroll
  for (int j = 0; j < 8; ++j)
#pragma unroll
    for (int k = 0; k < 16; ++k) lg[k] += h[j] * w2[j * 16 + k];
  float mx = lg[0];
#pragma unroll
  for (int k = 1; k < 16; ++k) mx = fmaxf(mx, lg[k]);
  float s = 0.f;
#pragma unroll
  for (int k = 0; k < 16; ++k) { lg[k] = __expf(lg[k] - mx); s += lg[k]; }
  const float inv = 1.f / s;
  float4* gp = (float4*)(gates + (size_t)b * 16);
#pragma unroll
  for (int i = 0; i < 4; ++i)
    gp[i] = make_float4(lg[i*4]*inv, lg[i*4+1]*inv, lg[i*4+2]*inv, lg[i*4+3]*inv);
}

// ---------------- 256x256 8-phase bf16 GEMM (T2+T3+T4+T5) ----------------
// Round-5 deltas vs round-3 (our best): (1) removed the inline-asm
// lgkmcnt(0) before each QUAD — the ds_reads are compiler-visible, so the
// waitcnt pass emits progressive counted lgkmcnt(N) before each dependent
// MFMA instead of a full drain (rule #18 applies only to asm ds_reads).
// All SCHED0 walls from round 3 are kept (round 4 proved they help).
// (2) optional fused epilogue: dot rows with w3 and atomicAdd into eo
// (layer-2+layer-3 fusion) instead of storing the output tile.
#define SCHED0 __builtin_amdgcn_sched_barrier(0)
#define BAR do { SCHED0; __builtin_amdgcn_s_barrier(); SCHED0; } while(0)
#define WAITVM(n) do { asm volatile("s_waitcnt vmcnt(" #n ")" ::: "memory"); SCHED0; } while(0)

#define STAGE_A(buf, h, kt) do { \
  _Pragma("unroll") for (int r_ = 0; r_ < 2; ++r_) { \
    const int rl_ = (h)*128 + r_*64 + wave*8; \
    async16(&As[(buf)*16384 + rl_*64], Ae + (size_t)(rl_ + rsub)*K + (kt) + ssw); \
  } } while(0)

#define STAGE_B(buf, h, kt) do { \
  _Pragma("unroll") for (int r_ = 0; r_ < 2; ++r_) { \
    const int rl_ = (h)*128 + r_*64 + wave*8; \
    async16(&Bs[(buf)*16384 + rl_*64], We + (size_t)(rl_ + rsub)*K + (kt) + ssw); \
  } } while(0)

#define LOAD_A(buf, MH) do { \
  _Pragma("unroll") for (int mi_ = 0; mi_ < 4; ++mi_) { \
    const int R_ = wr*128 + ((MH)*4 + mi_)*16 + fr; \
    _Pragma("unroll") for (int kk_ = 0; kk_ < 2; ++kk_) \
      af[mi_][kk_] = *(const short8v*)&As[(buf)*16384 + R_*64 + (((kk_*4 + kq) ^ fr7) * 8)]; \
  } } while(0)

#define LOAD_B(buf, NH) do { \
  _Pragma("unroll") for (int ni_ = 0; ni_ < 2; ++ni_) { \
    const int R_ = wc*64 + ((NH)*2 + ni_)*16 + fr; \
    _Pragma("unroll") for (int kk_ = 0; kk_ < 2; ++kk_) \
      bf[NH][ni_][kk_] = *(const short8v*)&Bs[(buf)*16384 + R_*64 + (((kk_*4 + kq) ^ fr7) * 8)]; \
  } } while(0)

#define QUAD(MH, NH) do { \
  __builtin_amdgcn_s_setprio(1); \
  _Pragma("unroll") for (int mi_ = 0; mi_ < 4; ++mi_) \
  _Pragma("unroll") for (int ni_ = 0; ni_ < 2; ++ni_) \
  _Pragma("unroll") for (int kk_ = 0; kk_ < 2; ++kk_) \
    acc[(MH)*4 + mi_][(NH)*2 + ni_] = __builtin_amdgcn_mfma_f32_16x16x32_bf16( \
        af[mi_][kk_], bf[NH][ni_][kk_], acc[(MH)*4 + mi_][(NH)*2 + ni_], 0, 0, 0); \
  __builtin_amdgcn_s_setprio(0); SCHED0; \
  } while(0)

__global__ __launch_bounds__(512, 2) void gemm8_kernel(
    const unsigned short* __restrict__ A, const unsigned short* __restrict__ Wt,
    const float* __restrict__ bias, unsigned short* __restrict__ Out,
    int K,
    long long strideA, long long strideW, long long strideB, long long strideO,
    const float* __restrict__ w3, float* __restrict__ eo_out)
{
  __shared__ unsigned short As[2 * 256 * 64];
  __shared__ unsigned short Bs[2 * 256 * 64];
  const int tid  = threadIdx.x;
  const int wave = tid >> 6, lane = tid & 63;
  const int wr = wave >> 2, wc = wave & 3;
  const int m0 = blockIdx.x * 256, n0 = blockIdx.y * 256;
  const int e  = blockIdx.z;
  const unsigned short* Ae = A + (size_t)e * strideA + (size_t)m0 * K;
  const unsigned short* We = Wt + (size_t)e * strideW + (size_t)n0 * K;
  const float* be = bias + (size_t)e * strideB;
  unsigned short* Oe = Out + (size_t)e * strideO;

  // staging lane geometry
  const int rsub = lane >> 3;                 // 0..7 row within 8-row block
  const int ssw  = ((lane & 7) ^ rsub) * 8;   // pre-swizzled global k-slot
  // fragment lane geometry
  const int fr  = lane & 15;
  const int kq  = lane >> 4;                  // 0..3
  const int fr7 = fr & 7;

  f32x4 acc[8][4] = {};
  short8v af[4][2];
  short8v bf[2][2][2];

  // ---- prologue: tile0 -> buf0 (B,A), tile1.B -> buf1 ----
  STAGE_B(0, 0, 0); STAGE_B(0, 1, 0);
  STAGE_A(0, 0, 0); STAGE_A(0, 1, 0);
  STAGE_B(1, 0, 64); STAGE_B(1, 1, 64);
  WAITVM(4);
  BAR;

  const int NITER = K / 128;
  for (int j = 0; j < NITER; ++j) {
    const bool st = (j < NITER - 1);
    const int kt_v  = j * 128 + 64;
    const int kt_u2 = j * 128 + 128;
    const int kt_v2 = j * 128 + 192;
    // P1: compute u quad(0,0); stage v.A half0 -> buf1
    LOAD_A(0, 0); LOAD_B(0, 0); SCHED0;
    STAGE_A(1, 0, kt_v);
    BAR; QUAD(0, 0); BAR;
    // P2: quad(0,1); stage v.A half1
    LOAD_B(0, 1); SCHED0;
    STAGE_A(1, 1, kt_v);
    BAR; QUAD(0, 1); BAR;
    // P3: quad(1,0); stage u2.B half0 -> buf0
    LOAD_A(0, 1); SCHED0;
    if (st) STAGE_B(0, 0, kt_u2);
    BAR; QUAD(1, 0); BAR;
    // P4: quad(1,1); stage u2.B half1; counted vmcnt
    if (st) STAGE_B(0, 1, kt_u2);
    BAR; QUAD(1, 1);
    if (st) { WAITVM(4); } else { WAITVM(0); }
    BAR;
    // P5: compute v quad(0,0); stage u2.A half0
    LOAD_A(1, 0); LOAD_B(1, 0); SCHED0;
    if (st) STAGE_A(0, 0, kt_u2);
    BAR; QUAD(0, 0); BAR;
    // P6: quad(0,1); stage u2.A half1
    LOAD_B(1, 1); SCHED0;
    if (st) STAGE_A(0, 1, kt_u2);
    BAR; QUAD(0, 1); BAR;
    // P7: quad(1,0); stage v2.B half0 -> buf1
    LOAD_A(1, 1); SCHED0;
    if (st) STAGE_B(1, 0, kt_v2);
    BAR; QUAD(1, 0); BAR;
    // P8: quad(1,1); stage v2.B half1; counted vmcnt
    if (st) STAGE_B(1, 1, kt_v2);
    BAR; QUAD(1, 1);
    if (st) { WAITVM(4); }
    BAR;
  }

  // ---- epilogue ----
  if (w3 == nullptr) {
    // bias + relu + bf16 store
#pragma unroll
    for (int ni = 0; ni < 4; ++ni) {
      const int n = n0 + wc * 64 + ni * 16 + fr;
      const float bv = be[n];
#pragma unroll
      for (int mi = 0; mi < 8; ++mi) {
#pragma unroll
        for (int r = 0; r < 4; ++r) {
          const int m = m0 + wr * 128 + mi * 16 + kq * 4 + r;
          float v = acc[mi][ni][r] + bv;
          v = v > 0.f ? v : 0.f;
          Oe[(size_t)m * HID + n] = f2bf(v);
        }
      }
    }
  } else {
    // fused layer-3: p[m] = sum_n relu(acc+bias) * w3[n]; atomicAdd to eo
    const float* w3e = w3 + (size_t)e * HID;
    float bv[4], wv[4];
#pragma unroll
    for (int ni = 0; ni < 4; ++ni) {
      const int n = n0 + wc * 64 + ni * 16 + fr;
      bv[ni] = be[n];
      wv[ni] = w3e[n];
    }
    float* eoe = eo_out + (size_t)e * B_ROWS;
#pragma unroll
    for (int mi = 0; mi < 8; ++mi) {
#pragma unroll
      for (int r = 0; r < 4; ++r) {
        float p = 0.f;
#pragma unroll
        for (int ni = 0; ni < 4; ++ni) {
          float v = acc[mi][ni][r] + bv[ni];
          v = v > 0.f ? v : 0.f;
          p += v * wv[ni];
        }
        // reduce across the 16 fr-lanes (bits 0..3 of lane)
        p += __shfl_xor(p, 1, 64);
        p += __shfl_xor(p, 2, 64);
        p += __shfl_xor(p, 4, 64);
        p += __shfl_xor(p, 8, 64);
        if (fr == 0) {
          const int m = m0 + wr * 128 + mi * 16 + kq * 4 + r;
          atomicAdd(&eoe[m], p);
        }
      }
    }
  }
}

// ---------------- out[b] = sum_e gates[b][e] * (eo[e][b] + eb3[e]) ----------------
__global__ __launch_bounds__(256) void final_kernel(
    const float* __restrict__ gates, const float* __restrict__ eo,
    const float* __restrict__ eb3, float* __restrict__ out)
{
  const int b = blockIdx.x * blockDim.x + threadIdx.x;
  if (b >= B_ROWS) return;
  float s = 0.f;
#pragma unroll
  for (int e = 0; e < NEXP; ++e)
    s += gates[(size_t)b * 16 + e] * (eo[(size_t)e * B_ROWS + b] + eb3[e]);
  out[b] = s;
}

extern "C" void kernel_launch(void* const* d_in, const int* in_sizes, int n_in,
                              void* d_out, int out_size, void* d_ws, size_t ws_size,
                              hipStream_t stream)
{
  const float* user_emb = (const float*)d_in[0];
  const float* item_emb = (const float*)d_in[1];
  const float* f_i_1    = (const float*)d_in[2];
  const float* g_i_1    = (const float*)d_in[3];
  const float* f_i_2    = (const float*)d_in[4];
  const float* g_i_2    = (const float*)d_in[5];
  const float* f_i_3    = (const float*)d_in[6];
  const float* g_i_3    = (const float*)d_in[7];
  const float* cate     = (const float*)d_in[8];
  const float* gate_w1  = (const float*)d_in[9];
  const float* gate_b1  = (const float*)d_in[10];
  const float* gate_w2  = (const float*)d_in[11];
  const float* gate_b2  = (const float*)d_in[12];
  const float* ew1      = (const float*)d_in[13];
  const float* eb1      = (const float*)d_in[14];
  const float* ew2      = (const float*)d_in[15];
  const float* eb2      = (const float*)d_in[16];
  const float* ew3      = (const float*)d_in[17];
  const float* eb3      = (const float*)d_in[18];
  float* out = (float*)d_out;

  char* ws = (char*)d_ws;
  size_t off = 0;
  unsigned short* comb = (unsigned short*)(ws + off); off += (size_t)B_ROWS * KPAD * 2;
  unsigned short* w1t  = (unsigned short*)(ws + off); off += (size_t)NEXP * HID * KPAD * 2;
  unsigned short* w2t  = (unsigned short*)(ws + off); off += (size_t)NEXP * HID * HID * 2;
  unsigned short* h1   = (unsigned short*)(ws + off); off += (size_t)EG * B_ROWS * HID * 2;
  float* gates = (float*)(ws + off); off += (size_t)B_ROWS * NEXP * 4;
  float* eo    = (float*)(ws + off); off += (size_t)NEXP * B_ROWS * 4;

  // 0. zero eo accumulators (atomicAdd targets)
  hipMemsetAsync(eo, 0, (size_t)NEXP * B_ROWS * 4, stream);

  // 1. pack combined input (bf16, K zero-padded to 4224)
  {
    const long long total = (long long)B_ROWS * (KPAD / 8);
    const int blocks = (int)((total + 255) / 256);
    pack_kernel<<<blocks, 256, 0, stream>>>(user_emb, item_emb, f_i_1, g_i_1,
                                            f_i_2, g_i_2, f_i_3, g_i_3, cate, comb);
  }
  // 2. weight transposes to [E][N][K] bf16
  transpose_kernel<<<dim3(KPAD / 64, HID / 64, NEXP), 256, 0, stream>>>(ew1, w1t, KTOT, HID, KPAD);
  transpose_kernel<<<dim3(HID / 64, HID / 64, NEXP), 256, 0, stream>>>(ew2, w2t, HID, HID, HID);
  // 3. gates
  gate_kernel<<<B_ROWS / 256, 256, 0, stream>>>(cate, gate_w1, gate_b1, gate_w2, gate_b2, gates);

  // 4. expert groups: layer1 (K=4224) -> h1; layer2+layer3 fused (K=512) -> eo
  for (int g = 0; g < NGRP; ++g) {
    gemm8_kernel<<<dim3(B_ROWS / 256, HID / 256, EG), 512, 0, stream>>>(
        comb, w1t + (size_t)g * EG * HID * KPAD, eb1 + (size_t)g * EG * HID, h1,
        KPAD, 0LL, (long long)HID * KPAD, (long long)HID, (long long)B_ROWS * HID,
        nullptr, nullptr);
    gemm8_kernel<<<dim3(B_ROWS / 256, HID / 256, EG), 512, 0, stream>>>(
        h1, w2t + (size_t)g * EG * HID * HID, eb2 + (size_t)g * EG * HID, nullptr,
        HID, (long long)B_ROWS * HID, (long long)HID * HID, (long long)HID, 0LL,
        ew3 + (size_t)g * EG * HID, eo + (size_t)g * EG * B_ROWS);
  }
  // 5. combine
  final_kernel<<<B_ROWS / 256, 256, 0, stream>>>(gates, eo, eb3, out);
}